// Round 6
// baseline (384.182 us; speedup 1.0000x reference)
//
#include <hip/hip_runtime.h>

// Pipeline: cvt(x,Wqkv,Wproj) -> GEMM qkv(bf16, m97 gload_lds) -> norm/split -> bias_prep ->
//           v_transpose -> flash attn (barrier-free, L2-direct K/V, fixed-max softmax)
//           -> GEMM proj(f32+bias)
// B=2 L=2048 C=1024 H=16 D=64. All matmuls bf16 MFMA 16x16x32, f32 accumulate.

typedef __bf16 bf16x8 __attribute__((ext_vector_type(8)));
typedef __bf16 bf16x4 __attribute__((ext_vector_type(4)));
typedef float  f32x4  __attribute__((ext_vector_type(4)));

#define BB 2
#define LL 2048
#define CC 1024
#define HH 16
#define DD 64
#define LOG2E 1.44269504088896f

__device__ __forceinline__ f32x4 mfma_16x16x32(bf16x8 a, bf16x8 b, f32x4 c) {
    return __builtin_amdgcn_mfma_f32_16x16x32_bf16(a, b, c, 0, 0, 0);
}

// async global->LDS, 16B per lane; LDS dest = wave-uniform base + lane*16
__device__ __forceinline__ void gload_lds16(const __bf16* g, __bf16* lds) {
    __builtin_amdgcn_global_load_lds(
        (const __attribute__((address_space(1))) unsigned int*)g,
        (__attribute__((address_space(3))) unsigned int*)lds,
        16, 0, 0);
}

// ---------------- f32 -> bf16 convert ----------------
__global__ __launch_bounds__(256) void cvt_bf16_kernel(const float* __restrict__ in,
                                                       __bf16* __restrict__ out, int n4) {
    int i = blockIdx.x * 256 + threadIdx.x;
    if (i >= n4) return;
    float4 v = reinterpret_cast<const float4*>(in)[i];
    bf16x4 o;
    o[0] = (__bf16)v.x; o[1] = (__bf16)v.y; o[2] = (__bf16)v.z; o[3] = (__bf16)v.w;
    reinterpret_cast<bf16x4*>(out)[i] = o;
}

// ---------------- bias prep: rowmax + bf16(bias - rowmax) ----------------
__global__ __launch_bounds__(256) void bias_prep_kernel(const float* __restrict__ bias,
                                                        __bf16* __restrict__ bias_bf) {
    __shared__ float wmax[4];
    const int l = blockIdx.x, tid = threadIdx.x;
    const int w = tid >> 6;
    float4 a = reinterpret_cast<const float4*>(bias + (size_t)l * 2048)[tid];
    float4 b = reinterpret_cast<const float4*>(bias + (size_t)l * 2048 + 1024)[tid];
    float m = fmaxf(fmaxf(fmaxf(a.x, a.y), fmaxf(a.z, a.w)),
                    fmaxf(fmaxf(b.x, b.y), fmaxf(b.z, b.w)));
#pragma unroll
    for (int off = 1; off < 64; off <<= 1) m = fmaxf(m, __shfl_xor(m, off, 64));
    if ((tid & 63) == 0) wmax[w] = m;
    __syncthreads();
    float M = fmaxf(fmaxf(wmax[0], wmax[1]), fmaxf(wmax[2], wmax[3]));
    bf16x4 o0, o1;
    o0[0] = (__bf16)(a.x - M); o0[1] = (__bf16)(a.y - M);
    o0[2] = (__bf16)(a.z - M); o0[3] = (__bf16)(a.w - M);
    o1[0] = (__bf16)(b.x - M); o1[1] = (__bf16)(b.y - M);
    o1[2] = (__bf16)(b.z - M); o1[3] = (__bf16)(b.w - M);
    reinterpret_cast<bf16x4*>(bias_bf + (size_t)l * 2048)[tid] = o0;
    reinterpret_cast<bf16x4*>(bias_bf + (size_t)l * 2048 + 1024)[tid] = o1;
}

// ---------------- GEMM: C[M,N] = A[M,K] * B[N,K]^T (+bias), m97 structure ----------------
template <int OUT_MODE>
__global__ __launch_bounds__(256) void gemm_bt_kernel(
    const __bf16* __restrict__ A, const __bf16* __restrict__ Bm,
    float* __restrict__ Cf, __bf16* __restrict__ Cb,
    const float* __restrict__ bias, int M, int N, int K) {
    __shared__ __bf16 As[128 * 64];   // LDS[row][c] = A[row][c ^ ((row&7)<<4)]  (byte view)
    __shared__ __bf16 Bs[128 * 64];
    const int tid = threadIdx.x;
    const int m0 = blockIdx.x * 128, n0 = blockIdx.y * 128;
    const int w  = tid >> 6, l = tid & 63;
    const int wr = (w >> 1) * 64, wc = (w & 1) * 64;
    const int lr = l & 15, lg = l >> 4;
    const int rmask = (lr & 7) << 4;
    f32x4 acc[4][4] = {};
    const int lrow = l >> 3;                      // 0..7
    const int celem = (((l & 7) ^ lrow) << 3);    // pre-swizzled col (elements)

    for (int kt = 0; kt < K; kt += 64) {
        __syncthreads();
#pragma unroll
        for (int i = 0; i < 4; ++i) {
            const int row = w * 32 + i * 8;
            gload_lds16(A + (size_t)(m0 + row + lrow) * K + kt + celem, &As[row * 64]);
            gload_lds16(Bm + (size_t)(n0 + row + lrow) * K + kt + celem, &Bs[row * 64]);
        }
        asm volatile("s_waitcnt vmcnt(0)" ::: "memory");
        __syncthreads();
#pragma unroll
        for (int kk = 0; kk < 2; ++kk) {          // kk*64 bytes
            bf16x8 af[4], bfr[4];
#pragma unroll
            for (int m = 0; m < 4; ++m)
                af[m] = *reinterpret_cast<const bf16x8*>(
                    (char*)As + (wr + m * 16 + lr) * 128 + ((kk * 64 + lg * 16) ^ rmask));
#pragma unroll
            for (int n = 0; n < 4; ++n)
                bfr[n] = *reinterpret_cast<const bf16x8*>(
                    (char*)Bs + (wc + n * 16 + lr) * 128 + ((kk * 64 + lg * 16) ^ rmask));
#pragma unroll
            for (int m = 0; m < 4; ++m)
#pragma unroll
                for (int n = 0; n < 4; ++n)
                    acc[m][n] = mfma_16x16x32(af[m], bfr[n], acc[m][n]);
        }
    }
#pragma unroll
    for (int m = 0; m < 4; ++m) {
#pragma unroll
        for (int n = 0; n < 4; ++n) {
            const int row = m0 + wr + m * 16 + lg * 4;
            const int col = n0 + wc + n * 16 + lr;
#pragma unroll
            for (int r = 0; r < 4; ++r) {
                float v = acc[m][n][r];
                if (OUT_MODE == 0) {
                    Cb[(size_t)(row + r) * N + col] = (__bf16)v;
                } else {
                    Cf[(size_t)(row + r) * N + col] = v + bias[col];
                }
            }
        }
    }
}

// ---------------- bias add + l2norm + scale, split into Q/K/V (B,H,L,D) bf16 ----------------
__global__ __launch_bounds__(256) void qkv_norm_kernel(
    const __bf16* __restrict__ qkv, const float* __restrict__ q_bias,
    const float* __restrict__ v_bias, const float* __restrict__ scale_mul,
    __bf16* __restrict__ Q, __bf16* __restrict__ K, __bf16* __restrict__ V) {
    const int bl = blockIdx.x;
    const int tid = threadIdx.x;
    const int w = tid >> 6, d = tid & 63;
    const int b = bl >> 11, l = bl & 2047;
    for (int g = w; g < 48; g += 4) {
        const int s = g >> 4, h = g & 15;
        float v = (float)qkv[(size_t)bl * 3072 + g * 64 + d];
        if (s == 0) v += q_bias[h * 64 + d];
        if (s == 2) v += v_bias[h * 64 + d];
        if (s < 2) {
            float ss = v * v;
#pragma unroll
            for (int off = 1; off < 64; off <<= 1) ss += __shfl_xor(ss, off, 64);
            float nrm = sqrtf(ss);
            v = v / fmaxf(nrm, 1e-12f);
            if (s == 0) v *= __expf(fminf(scale_mul[h], 4.60517019f));
        }
        __bf16* dst = (s == 0) ? Q : ((s == 1) ? K : V);
        dst[((size_t)(b * 16 + h) * 2048 + l) * 64 + d] = (__bf16)v;
    }
}

// ---------------- V transpose: (B,H,L,D) -> (B,H,D,L) ----------------
__global__ __launch_bounds__(256) void v_transpose_kernel(const __bf16* __restrict__ Vin,
                                                          __bf16* __restrict__ Vt) {
    __shared__ __bf16 T[64][72];
    const int lb = blockIdx.x, bh = blockIdx.y;
    const int tid = threadIdx.x;
    const size_t base = (size_t)bh * LL * DD;
    const int row = tid >> 2, c = (tid & 3) * 16;
    {
        const __bf16* src = Vin + base + (size_t)(lb * 64 + row) * 64 + c;
        *reinterpret_cast<bf16x8*>(&T[row][c])     = *reinterpret_cast<const bf16x8*>(src);
        *reinterpret_cast<bf16x8*>(&T[row][c + 8]) = *reinterpret_cast<const bf16x8*>(src + 8);
    }
    __syncthreads();
    bf16x8 o0, o1;
#pragma unroll
    for (int j = 0; j < 8; ++j) {
        o0[j] = T[c + j][row];
        o1[j] = T[c + 8 + j][row];
    }
    __bf16* dst = Vt + base + (size_t)row * 2048 + lb * 64 + c;
    *reinterpret_cast<bf16x8*>(dst)     = o0;
    *reinterpret_cast<bf16x8*>(dst + 8) = o1;
}

// ---------------- flash attention: barrier-free, L2-direct K/V fragments ----------------
// grid 1024 blocks; internal bijective XCD swizzle groups 4 heads per XCD (K/V L2-resident).
// 4 waves; wave w owns q-rows [qb*64+w*16, +16). Swapped QK^T: lane q=lr, k=16t+4lg+r.
__global__ __launch_bounds__(256, 4) void attn_kernel(
    const __bf16* __restrict__ Q, const __bf16* __restrict__ K,
    const __bf16* __restrict__ Vt, const __bf16* __restrict__ bias_bf,
    const float* __restrict__ scale_mul, __bf16* __restrict__ Octx) {
    __shared__ __bf16 Ps[64 * 64];          // 8KB; row = q_local, wave-private rows
    const int tid = threadIdx.x;
    // XCD swizzle: dispatch index -> (bh, qb) so each XCD serves 4 contiguous heads
    const int flat = blockIdx.x + (blockIdx.y << 5);
    const int swz  = (flat & 7) * 128 + (flat >> 3);
    const int bh = swz >> 5, qb = swz & 31;
    const int w = tid >> 6, l = tid & 63;
    const int lr = l & 15, lg = l >> 4;
    const int rmask = (lr & 7) << 4;
    const int b = bh >> 4, h = bh & 15;
    const size_t base = (size_t)bh * LL * DD;
    const float smh = __expf(fminf(scale_mul[h], 4.60517019f));
    const float cexp = -smh * LOG2E;

    const int gq = qb * 64 + w * 16 + lr;   // this lane's q row
    bf16x8 qf[2];
    qf[0] = *reinterpret_cast<const bf16x8*>(Q + base + (size_t)gq * 64 + lg * 8);
    qf[1] = *reinterpret_cast<const bf16x8*>(Q + base + (size_t)gq * 64 + 32 + lg * 8);
    const __bf16* brow = bias_bf + (size_t)gq * 2048;

    // per-lane fragment base pointers
    const __bf16* Kp = K  + base + (size_t)lr * 64 + lg * 8;          // + (kb*64+t*16)*64
    const __bf16* Vp = Vt + base + (size_t)lr * 2048 + lg * 8;        // + t*16*2048 + kb*64

    f32x4 Oa[4] = {};
    float lsum = 0.f;
    char* psb = (char*)Ps + (w * 16 + lr) * 128;

    bf16x4 bcur[4];
#pragma unroll
    for (int t = 0; t < 4; ++t)
        bcur[t] = *reinterpret_cast<const bf16x4*>(brow + t * 16 + lg * 4);

    for (int kb = 0; kb < 32; ++kb) {
        // ---- K fragments direct from global (L2-resident) ----
        bf16x8 kf0[4], kf1[4];
#pragma unroll
        for (int t = 0; t < 4; ++t) {
            const __bf16* kr = Kp + (size_t)(kb * 64 + t * 16) * 64;
            kf0[t] = *reinterpret_cast<const bf16x8*>(kr);
            kf1[t] = *reinterpret_cast<const bf16x8*>(kr + 32);
        }
        // S^T = K Q^T
        f32x4 sa[4] = {};
#pragma unroll
        for (int t = 0; t < 4; ++t) {
            sa[t] = mfma_16x16x32(kf0[t], qf[0], sa[t]);
            sa[t] = mfma_16x16x32(kf1[t], qf[1], sa[t]);
        }

        // bias prefetch for next iter
        bf16x4 bnext[4];
        if (kb < 31) {
#pragma unroll
            for (int t = 0; t < 4; ++t)
                bnext[t] = *reinterpret_cast<const bf16x4*>(brow + (kb + 1) * 64 + t * 16 + lg * 4);
        }

        // softmax: p = exp2((s+bias)·log2e − smh·log2e); exponent ≤ ~0.006·smh, safe
#pragma unroll
        for (int t = 0; t < 4; ++t) {
            bf16x4 pb;
#pragma unroll
            for (int r = 0; r < 4; ++r) {
                float s = sa[t][r] + (float)bcur[t][r];
                float p = exp2f(fmaf(s, LOG2E, cexp));
                lsum += p;
                pb[r] = (__bf16)p;
            }
            *reinterpret_cast<bf16x4*>(psb + ((t * 32 + lg * 8) ^ rmask)) = pb;
        }

        // ---- V fragments direct from global (issued while P lands in LDS) ----
        bf16x8 vf0[4], vf1[4];
#pragma unroll
        for (int t = 0; t < 4; ++t) {
            const __bf16* vr = Vp + (size_t)(t * 16) * 2048 + kb * 64;
            vf0[t] = *reinterpret_cast<const bf16x8*>(vr);
            vf1[t] = *reinterpret_cast<const bf16x8*>(vr + 32);
        }

        // P fragments (wave-private rows; same-wave RAW via lgkmcnt)
        bf16x8 pf0 = *reinterpret_cast<const bf16x8*>(psb + ((lg * 16) ^ rmask));
        bf16x8 pf1 = *reinterpret_cast<const bf16x8*>(psb + ((64 + lg * 16) ^ rmask));

        // O += P·V
#pragma unroll
        for (int t = 0; t < 4; ++t) {
            Oa[t] = mfma_16x16x32(pf0, vf0[t], Oa[t]);
            Oa[t] = mfma_16x16x32(pf1, vf1[t], Oa[t]);
        }

        if (kb < 31) {
#pragma unroll
            for (int t = 0; t < 4; ++t) bcur[t] = bnext[t];
        }
    }

    // reduce lsum: partials for q=lr live at lanes lr, lr+16, lr+32, lr+48
    lsum += __shfl_xor(lsum, 16, 64);
    lsum += __shfl_xor(lsum, 32, 64);
    float inv[4];
#pragma unroll
    for (int r = 0; r < 4; ++r) inv[r] = 1.0f / __shfl(lsum, lg * 4 + r, 64);

#pragma unroll
    for (int t = 0; t < 4; ++t)
#pragma unroll
        for (int r = 0; r < 4; ++r) {
            const int row = qb * 64 + w * 16 + lg * 4 + r;
            float o = Oa[t][r] * inv[r];
            Octx[((size_t)(b * 2048 + row)) * 1024 + h * 64 + t * 16 + lr] = (__bf16)o;
        }
}

// ---------------- launch ----------------
extern "C" void kernel_launch(void* const* d_in, const int* in_sizes, int n_in,
                              void* d_out, int out_size, void* d_ws, size_t ws_size,
                              hipStream_t stream) {
    const float* x         = (const float*)d_in[0];
    const float* attn_bias = (const float*)d_in[1];
    const float* W_qkv     = (const float*)d_in[2];
    const float* q_bias    = (const float*)d_in[3];
    const float* v_bias    = (const float*)d_in[4];
    const float* scale_mul = (const float*)d_in[5];
    const float* W_proj    = (const float*)d_in[6];
    const float* b_proj    = (const float*)d_in[7];
    float* out = (float*)d_out;

    char* ws = (char*)d_ws;
    size_t off = 0;
    auto alloc = [&](size_t bytes) {
        void* p = ws + off;
        off = (off + bytes + 255) & ~(size_t)255;
        return p;
    };
    __bf16* xb     = (__bf16*)alloc((size_t)4096 * 1024 * 2);
    __bf16* wqkvb  = (__bf16*)alloc((size_t)3072 * 1024 * 2);
    __bf16* wprojb = (__bf16*)alloc((size_t)1024 * 1024 * 2);
    __bf16* qkvb   = (__bf16*)alloc((size_t)4096 * 3072 * 2);   // 24 MB
    __bf16* Qw     = (__bf16*)alloc((size_t)BB * HH * LL * DD * 2);
    __bf16* Kw     = (__bf16*)alloc((size_t)BB * HH * LL * DD * 2);
    __bf16* Vw     = (__bf16*)alloc((size_t)BB * HH * LL * DD * 2);
    __bf16* Oc     = (__bf16*)alloc((size_t)4096 * 1024 * 2);
    // alias: after qkv_norm consumes qkvb, reuse its space for bias_bf and Vt
    __bf16* bias_bf = qkvb;                                      // 8 MB
    __bf16* Vt      = qkvb + (size_t)2048 * 2048;                // 8 MB

    cvt_bf16_kernel<<<4096, 256, 0, stream>>>(x, xb, 4096 * 1024 / 4);
    cvt_bf16_kernel<<<3072, 256, 0, stream>>>(W_qkv, wqkvb, 3072 * 1024 / 4);
    cvt_bf16_kernel<<<1024, 256, 0, stream>>>(W_proj, wprojb, 1024 * 1024 / 4);

    gemm_bt_kernel<0><<<dim3(32, 24), 256, 0, stream>>>(
        xb, wqkvb, nullptr, qkvb, nullptr, 4096, 3072, 1024);

    qkv_norm_kernel<<<4096, 256, 0, stream>>>(qkvb, q_bias, v_bias, scale_mul, Qw, Kw, Vw);

    bias_prep_kernel<<<2048, 256, 0, stream>>>(attn_bias, bias_bf);
    v_transpose_kernel<<<dim3(32, 32), 256, 0, stream>>>(Vw, Vt);

    attn_kernel<<<dim3(32, 32), 256, 0, stream>>>(Qw, Kw, Vt, bias_bf, scale_mul, Oc);

    gemm_bt_kernel<1><<<dim3(32, 8), 256, 0, stream>>>(
        Oc, wprojb, out, nullptr, b_proj, 4096, 1024, 1024);
}

// Round 7
// 209.332 us; speedup vs baseline: 1.8353x; 1.8353x over previous
//
#include <hip/hip_runtime.h>

// Pipeline: cvt(x,Wqkv,Wproj) -> GEMM qkv(bf16, m97 gload_lds) -> norm/split (Q pre-scaled
//           by smh*log2e) -> bias_prep (bias*log2e) -> v_transpose ->
//           flash attn (QBLK=128, swapped-QK^T, bias-in-accumulator, dbuf, 1 barrier/iter)
//           -> GEMM proj(f32+bias)
// B=2 L=2048 C=1024 H=16 D=64. All matmuls bf16 MFMA 16x16x32, f32 accumulate.

typedef __bf16 bf16x8 __attribute__((ext_vector_type(8)));
typedef __bf16 bf16x4 __attribute__((ext_vector_type(4)));
typedef float  f32x4  __attribute__((ext_vector_type(4)));

#define BB 2
#define LL 2048
#define CC 1024
#define HH 16
#define DD 64
#define LOG2E 1.44269504088896f

__device__ __forceinline__ f32x4 mfma_16x16x32(bf16x8 a, bf16x8 b, f32x4 c) {
    return __builtin_amdgcn_mfma_f32_16x16x32_bf16(a, b, c, 0, 0, 0);
}

// async global->LDS, 16B per lane; LDS dest = wave-uniform base + lane*16
__device__ __forceinline__ void gload_lds16(const __bf16* g, __bf16* lds) {
    __builtin_amdgcn_global_load_lds(
        (const __attribute__((address_space(1))) unsigned int*)g,
        (__attribute__((address_space(3))) unsigned int*)lds,
        16, 0, 0);
}

// ---------------- f32 -> bf16 convert ----------------
__global__ __launch_bounds__(256) void cvt_bf16_kernel(const float* __restrict__ in,
                                                       __bf16* __restrict__ out, int n4) {
    int i = blockIdx.x * 256 + threadIdx.x;
    if (i >= n4) return;
    float4 v = reinterpret_cast<const float4*>(in)[i];
    bf16x4 o;
    o[0] = (__bf16)v.x; o[1] = (__bf16)v.y; o[2] = (__bf16)v.z; o[3] = (__bf16)v.w;
    reinterpret_cast<bf16x4*>(out)[i] = o;
}

// ---------------- bias prep: rowmax + bf16((bias - rowmax)*log2e) ----------------
__global__ __launch_bounds__(256) void bias_prep_kernel(const float* __restrict__ bias,
                                                        __bf16* __restrict__ bias_bf) {
    __shared__ float wmax[4];
    const int l = blockIdx.x, tid = threadIdx.x;
    const int w = tid >> 6;
    float4 a = reinterpret_cast<const float4*>(bias + (size_t)l * 2048)[tid];
    float4 b = reinterpret_cast<const float4*>(bias + (size_t)l * 2048 + 1024)[tid];
    float m = fmaxf(fmaxf(fmaxf(a.x, a.y), fmaxf(a.z, a.w)),
                    fmaxf(fmaxf(b.x, b.y), fmaxf(b.z, b.w)));
#pragma unroll
    for (int off = 1; off < 64; off <<= 1) m = fmaxf(m, __shfl_xor(m, off, 64));
    if ((tid & 63) == 0) wmax[w] = m;
    __syncthreads();
    float M = fmaxf(fmaxf(wmax[0], wmax[1]), fmaxf(wmax[2], wmax[3]));
    bf16x4 o0, o1;
    o0[0] = (__bf16)((a.x - M) * LOG2E); o0[1] = (__bf16)((a.y - M) * LOG2E);
    o0[2] = (__bf16)((a.z - M) * LOG2E); o0[3] = (__bf16)((a.w - M) * LOG2E);
    o1[0] = (__bf16)((b.x - M) * LOG2E); o1[1] = (__bf16)((b.y - M) * LOG2E);
    o1[2] = (__bf16)((b.z - M) * LOG2E); o1[3] = (__bf16)((b.w - M) * LOG2E);
    reinterpret_cast<bf16x4*>(bias_bf + (size_t)l * 2048)[tid] = o0;
    reinterpret_cast<bf16x4*>(bias_bf + (size_t)l * 2048 + 1024)[tid] = o1;
}

// ---------------- GEMM: C[M,N] = A[M,K] * B[N,K]^T (+bias), m97 structure ----------------
template <int OUT_MODE>
__global__ __launch_bounds__(256) void gemm_bt_kernel(
    const __bf16* __restrict__ A, const __bf16* __restrict__ Bm,
    float* __restrict__ Cf, __bf16* __restrict__ Cb,
    const float* __restrict__ bias, int M, int N, int K) {
    __shared__ __bf16 As[128 * 64];   // LDS[row][c] = A[row][c ^ ((row&7)<<4)]  (byte view)
    __shared__ __bf16 Bs[128 * 64];
    const int tid = threadIdx.x;
    const int m0 = blockIdx.x * 128, n0 = blockIdx.y * 128;
    const int w  = tid >> 6, l = tid & 63;
    const int wr = (w >> 1) * 64, wc = (w & 1) * 64;
    const int lr = l & 15, lg = l >> 4;
    const int rmask = (lr & 7) << 4;
    f32x4 acc[4][4] = {};
    const int lrow = l >> 3;                      // 0..7
    const int celem = (((l & 7) ^ lrow) << 3);    // pre-swizzled col (elements)

    for (int kt = 0; kt < K; kt += 64) {
        __syncthreads();
#pragma unroll
        for (int i = 0; i < 4; ++i) {
            const int row = w * 32 + i * 8;
            gload_lds16(A + (size_t)(m0 + row + lrow) * K + kt + celem, &As[row * 64]);
            gload_lds16(Bm + (size_t)(n0 + row + lrow) * K + kt + celem, &Bs[row * 64]);
        }
        asm volatile("s_waitcnt vmcnt(0)" ::: "memory");
        __syncthreads();
#pragma unroll
        for (int kk = 0; kk < 2; ++kk) {          // kk*64 bytes
            bf16x8 af[4], bfr[4];
#pragma unroll
            for (int m = 0; m < 4; ++m)
                af[m] = *reinterpret_cast<const bf16x8*>(
                    (char*)As + (wr + m * 16 + lr) * 128 + ((kk * 64 + lg * 16) ^ rmask));
#pragma unroll
            for (int n = 0; n < 4; ++n)
                bfr[n] = *reinterpret_cast<const bf16x8*>(
                    (char*)Bs + (wc + n * 16 + lr) * 128 + ((kk * 64 + lg * 16) ^ rmask));
#pragma unroll
            for (int m = 0; m < 4; ++m)
#pragma unroll
                for (int n = 0; n < 4; ++n)
                    acc[m][n] = mfma_16x16x32(af[m], bfr[n], acc[m][n]);
        }
    }
#pragma unroll
    for (int m = 0; m < 4; ++m) {
#pragma unroll
        for (int n = 0; n < 4; ++n) {
            const int row = m0 + wr + m * 16 + lg * 4;
            const int col = n0 + wc + n * 16 + lr;
#pragma unroll
            for (int r = 0; r < 4; ++r) {
                float v = acc[m][n][r];
                if (OUT_MODE == 0) {
                    Cb[(size_t)(row + r) * N + col] = (__bf16)v;
                } else {
                    Cf[(size_t)(row + r) * N + col] = v + bias[col];
                }
            }
        }
    }
}

// ---------------- bias add + l2norm + scale, split into Q/K/V (B,H,L,D) bf16 ----------------
// Q additionally pre-scaled by log2e so the attn exponent is exp2-ready.
__global__ __launch_bounds__(256) void qkv_norm_kernel(
    const __bf16* __restrict__ qkv, const float* __restrict__ q_bias,
    const float* __restrict__ v_bias, const float* __restrict__ scale_mul,
    __bf16* __restrict__ Q, __bf16* __restrict__ K, __bf16* __restrict__ V) {
    const int bl = blockIdx.x;
    const int tid = threadIdx.x;
    const int w = tid >> 6, d = tid & 63;
    const int b = bl >> 11, l = bl & 2047;
    for (int g = w; g < 48; g += 4) {
        const int s = g >> 4, h = g & 15;
        float v = (float)qkv[(size_t)bl * 3072 + g * 64 + d];
        if (s == 0) v += q_bias[h * 64 + d];
        if (s == 2) v += v_bias[h * 64 + d];
        if (s < 2) {
            float ss = v * v;
#pragma unroll
            for (int off = 1; off < 64; off <<= 1) ss += __shfl_xor(ss, off, 64);
            float nrm = sqrtf(ss);
            v = v / fmaxf(nrm, 1e-12f);
            if (s == 0) v *= __expf(fminf(scale_mul[h], 4.60517019f)) * LOG2E;
        }
        __bf16* dst = (s == 0) ? Q : ((s == 1) ? K : V);
        dst[((size_t)(b * 16 + h) * 2048 + l) * 64 + d] = (__bf16)v;
    }
}

// ---------------- V transpose: (B,H,L,D) -> (B,H,D,L) ----------------
__global__ __launch_bounds__(256) void v_transpose_kernel(const __bf16* __restrict__ Vin,
                                                          __bf16* __restrict__ Vt) {
    __shared__ __bf16 T[64][72];
    const int lb = blockIdx.x, bh = blockIdx.y;
    const int tid = threadIdx.x;
    const size_t base = (size_t)bh * LL * DD;
    const int row = tid >> 2, c = (tid & 3) * 16;
    {
        const __bf16* src = Vin + base + (size_t)(lb * 64 + row) * 64 + c;
        *reinterpret_cast<bf16x8*>(&T[row][c])     = *reinterpret_cast<const bf16x8*>(src);
        *reinterpret_cast<bf16x8*>(&T[row][c + 8]) = *reinterpret_cast<const bf16x8*>(src + 8);
    }
    __syncthreads();
    bf16x8 o0, o1;
#pragma unroll
    for (int j = 0; j < 8; ++j) {
        o0[j] = T[c + j][row];
        o1[j] = T[c + 8 + j][row];
    }
    __bf16* dst = Vt + base + (size_t)row * 2048 + lb * 64 + c;
    *reinterpret_cast<bf16x8*>(dst)     = o0;
    *reinterpret_cast<bf16x8*>(dst + 8) = o1;
}

// ---------------- flash attention: QBLK=128 (2 q-groups/wave), swapped QK^T,
//   bias-in-accumulator fixed-max softmax, reg-staged dbuf K/V, 1 barrier/iter ----------
// grid (bh=32, qb=16); 256 threads = 4 waves; wave w owns q-rows [qb*128+w*32, +32).
__global__ __launch_bounds__(256, 3) void attn_kernel(
    const __bf16* __restrict__ Q, const __bf16* __restrict__ K,
    const __bf16* __restrict__ Vt, const __bf16* __restrict__ biasL,
    const float* __restrict__ scale_mul, __bf16* __restrict__ Octx) {
    __shared__ __bf16 KVs[2][2][64 * 64];   // [buf][K/V]; LDS[row][c]=G[row][c^((row&7)<<4)]
    __shared__ __bf16 Ps[64 * 64];          // 8KB, reused by both q-groups (same-wave in-order)
    const int bh = blockIdx.x, qb = blockIdx.y;
    const int tid = threadIdx.x;
    const int w = tid >> 6, l = tid & 63;
    const int lr = l & 15, lg = l >> 4;
    const int rmask = (lr & 7) << 4;
    const int b = bh >> 4, h = bh & 15;
    const size_t base = (size_t)bh * LL * DD;
    const float smh = __expf(fminf(scale_mul[h], 4.60517019f));
    const float cexp = -smh * LOG2E;

    const int gq0 = qb * 128 + w * 32 + lr;   // group 0 q row; group 1 = +16
    bf16x8 qf0[2], qf1[2];
    qf0[0] = *reinterpret_cast<const bf16x8*>(Q + base + (size_t)gq0 * 64 + lg * 8);
    qf0[1] = *reinterpret_cast<const bf16x8*>(Q + base + (size_t)gq0 * 64 + 32 + lg * 8);
    qf1[0] = *reinterpret_cast<const bf16x8*>(Q + base + (size_t)(gq0 + 16) * 64 + lg * 8);
    qf1[1] = *reinterpret_cast<const bf16x8*>(Q + base + (size_t)(gq0 + 16) * 64 + 32 + lg * 8);
    const __bf16* brow0 = biasL + (size_t)gq0 * 2048 + lg * 4;
    const __bf16* brow1 = biasL + (size_t)(gq0 + 16) * 2048 + lg * 4;

    // staging geometry: 4 threads per row, 32B chunks (reg-staged, issue-early/write-late)
    const int srow = tid >> 2;
    const int scb  = (tid & 3) * 32;               // byte col base
    const int smask = (srow & 7) << 4;
    const __bf16* kgbase = K  + base + (size_t)srow * 64   + (tid & 3) * 16;
    const __bf16* vgbase = Vt + base + (size_t)srow * 2048 + (tid & 3) * 16;

    bf16x8 k0, k1, v0, v1;
    auto stage_regs = [&](int kb) {
        const __bf16* kg = kgbase + (size_t)kb * 64 * 64;
        k0 = *reinterpret_cast<const bf16x8*>(kg);
        k1 = *reinterpret_cast<const bf16x8*>(kg + 8);
        const __bf16* vg = vgbase + kb * 64;
        v0 = *reinterpret_cast<const bf16x8*>(vg);
        v1 = *reinterpret_cast<const bf16x8*>(vg + 8);
    };
    auto write_lds = [&](int buf) {
        char* kp = (char*)KVs[buf][0] + srow * 128;
        char* vp = (char*)KVs[buf][1] + srow * 128;
        *reinterpret_cast<bf16x8*>(kp + (scb ^ smask))        = k0;
        *reinterpret_cast<bf16x8*>(kp + ((scb + 16) ^ smask)) = k1;
        *reinterpret_cast<bf16x8*>(vp + (scb ^ smask))        = v0;
        *reinterpret_cast<bf16x8*>(vp + ((scb + 16) ^ smask)) = v1;
    };

    stage_regs(0);
    write_lds(0);

    f32x4 Oa0[4] = {}, Oa1[4] = {};
    float ls0 = 0.f, ls1 = 0.f;
    int cur = 0;
    char* psb = (char*)Ps + (w * 16 + lr) * 128;

    for (int kb = 0; kb < 32; ++kb) {
        __syncthreads();                    // buf[cur] published; buf[cur^1] free
        if (kb < 31) stage_regs(kb + 1);    // issue next-tile loads early (T14)

        // bias for this tile, both groups (L2-resident 8B loads)
        bf16x4 b0[4], b1[4];
#pragma unroll
        for (int t = 0; t < 4; ++t) {
            b0[t] = *reinterpret_cast<const bf16x4*>(brow0 + kb * 64 + t * 16);
            b1[t] = *reinterpret_cast<const bf16x4*>(brow1 + kb * 64 + t * 16);
        }

        const char* Kc = (const char*)KVs[cur][0];
        const char* Vc = (const char*)KVs[cur][1];

        // accumulator init = bias*log2e + cexp  (bias folded into MFMA C-input)
        f32x4 sa0[4], sa1[4];
#pragma unroll
        for (int t = 0; t < 4; ++t)
#pragma unroll
            for (int r = 0; r < 4; ++r) {
                sa0[t][r] = (float)b0[t][r] + cexp;
                sa1[t][r] = (float)b1[t][r] + cexp;
            }

        // S^T·log2e = K (Q·log2e)^T : lane holds q=lr, k = 16t+4lg+r; K frags shared
#pragma unroll
        for (int t = 0; t < 4; ++t) {
            const char* kr = Kc + (t * 16 + lr) * 128;
            bf16x8 kf0 = *reinterpret_cast<const bf16x8*>(kr + ((lg * 16) ^ rmask));
            bf16x8 kf1 = *reinterpret_cast<const bf16x8*>(kr + ((64 + lg * 16) ^ rmask));
            sa0[t] = mfma_16x16x32(kf0, qf0[0], sa0[t]);
            sa0[t] = mfma_16x16x32(kf1, qf0[1], sa0[t]);
            sa1[t] = mfma_16x16x32(kf0, qf1[0], sa1[t]);
            sa1[t] = mfma_16x16x32(kf1, qf1[1], sa1[t]);
        }

        // ---- group 0: softmax (p = exp2(sa)) + PV ----
#pragma unroll
        for (int t = 0; t < 4; ++t) {
            bf16x4 pb;
#pragma unroll
            for (int r = 0; r < 4; ++r) {
                float p = exp2f(sa0[t][r]);
                ls0 += p;
                pb[r] = (__bf16)p;
            }
            *reinterpret_cast<bf16x4*>(psb + ((t * 32 + lg * 8) ^ rmask)) = pb;
        }
        {
            bf16x8 pf0 = *reinterpret_cast<const bf16x8*>(psb + ((lg * 16) ^ rmask));
            bf16x8 pf1 = *reinterpret_cast<const bf16x8*>(psb + ((64 + lg * 16) ^ rmask));
#pragma unroll
            for (int t = 0; t < 4; ++t) {
                const char* vr = Vc + (t * 16 + lr) * 128;
                bf16x8 vf0 = *reinterpret_cast<const bf16x8*>(vr + ((lg * 16) ^ rmask));
                bf16x8 vf1 = *reinterpret_cast<const bf16x8*>(vr + ((64 + lg * 16) ^ rmask));
                Oa0[t] = mfma_16x16x32(pf0, vf0, Oa0[t]);
                Oa0[t] = mfma_16x16x32(pf1, vf1, Oa0[t]);
            }
        }

        // ---- group 1: softmax + PV (Ps WAR-safe: same-wave LDS ops are in-order) ----
#pragma unroll
        for (int t = 0; t < 4; ++t) {
            bf16x4 pb;
#pragma unroll
            for (int r = 0; r < 4; ++r) {
                float p = exp2f(sa1[t][r]);
                ls1 += p;
                pb[r] = (__bf16)p;
            }
            *reinterpret_cast<bf16x4*>(psb + ((t * 32 + lg * 8) ^ rmask)) = pb;
        }
        {
            bf16x8 pf0 = *reinterpret_cast<const bf16x8*>(psb + ((lg * 16) ^ rmask));
            bf16x8 pf1 = *reinterpret_cast<const bf16x8*>(psb + ((64 + lg * 16) ^ rmask));
#pragma unroll
            for (int t = 0; t < 4; ++t) {
                const char* vr = Vc + (t * 16 + lr) * 128;
                bf16x8 vf0 = *reinterpret_cast<const bf16x8*>(vr + ((lg * 16) ^ rmask));
                bf16x8 vf1 = *reinterpret_cast<const bf16x8*>(vr + ((64 + lg * 16) ^ rmask));
                Oa1[t] = mfma_16x16x32(pf0, vf0, Oa1[t]);
                Oa1[t] = mfma_16x16x32(pf1, vf1, Oa1[t]);
            }
        }

        if (kb < 31) write_lds(cur ^ 1);    // write-late; dep on loads forces vmcnt
        cur ^= 1;
    }

    // reduce lsums: partials for q=lr live at lanes lr, lr+16, lr+32, lr+48
    ls0 += __shfl_xor(ls0, 16, 64); ls0 += __shfl_xor(ls0, 32, 64);
    ls1 += __shfl_xor(ls1, 16, 64); ls1 += __shfl_xor(ls1, 32, 64);
    float inv0[4], inv1[4];
#pragma unroll
    for (int r = 0; r < 4; ++r) {
        inv0[r] = 1.0f / __shfl(ls0, lg * 4 + r, 64);
        inv1[r] = 1.0f / __shfl(ls1, lg * 4 + r, 64);
    }

#pragma unroll
    for (int t = 0; t < 4; ++t)
#pragma unroll
        for (int r = 0; r < 4; ++r) {
            const int row0 = qb * 128 + w * 32 + lg * 4 + r;
            Octx[((size_t)(b * 2048 + row0)) * 1024 + h * 64 + t * 16 + lr] =
                (__bf16)(Oa0[t][r] * inv0[r]);
            Octx[((size_t)(b * 2048 + row0 + 16)) * 1024 + h * 64 + t * 16 + lr] =
                (__bf16)(Oa1[t][r] * inv1[r]);
        }
}

// ---------------- launch ----------------
extern "C" void kernel_launch(void* const* d_in, const int* in_sizes, int n_in,
                              void* d_out, int out_size, void* d_ws, size_t ws_size,
                              hipStream_t stream) {
    const float* x         = (const float*)d_in[0];
    const float* attn_bias = (const float*)d_in[1];
    const float* W_qkv     = (const float*)d_in[2];
    const float* q_bias    = (const float*)d_in[3];
    const float* v_bias    = (const float*)d_in[4];
    const float* scale_mul = (const float*)d_in[5];
    const float* W_proj    = (const float*)d_in[6];
    const float* b_proj    = (const float*)d_in[7];
    float* out = (float*)d_out;

    char* ws = (char*)d_ws;
    size_t off = 0;
    auto alloc = [&](size_t bytes) {
        void* p = ws + off;
        off = (off + bytes + 255) & ~(size_t)255;
        return p;
    };
    __bf16* xb     = (__bf16*)alloc((size_t)4096 * 1024 * 2);
    __bf16* wqkvb  = (__bf16*)alloc((size_t)3072 * 1024 * 2);
    __bf16* wprojb = (__bf16*)alloc((size_t)1024 * 1024 * 2);
    __bf16* qkvb   = (__bf16*)alloc((size_t)4096 * 3072 * 2);   // 24 MB
    __bf16* Qw     = (__bf16*)alloc((size_t)BB * HH * LL * DD * 2);
    __bf16* Kw     = (__bf16*)alloc((size_t)BB * HH * LL * DD * 2);
    __bf16* Vw     = (__bf16*)alloc((size_t)BB * HH * LL * DD * 2);
    __bf16* Oc     = (__bf16*)alloc((size_t)4096 * 1024 * 2);
    // alias: after qkv_norm consumes qkvb, reuse its space for bias_bf and Vt
    __bf16* bias_bf = qkvb;                                      // 8 MB
    __bf16* Vt      = qkvb + (size_t)2048 * 2048;                // 8 MB

    cvt_bf16_kernel<<<4096, 256, 0, stream>>>(x, xb, 4096 * 1024 / 4);
    cvt_bf16_kernel<<<3072, 256, 0, stream>>>(W_qkv, wqkvb, 3072 * 1024 / 4);
    cvt_bf16_kernel<<<1024, 256, 0, stream>>>(W_proj, wprojb, 1024 * 1024 / 4);

    gemm_bt_kernel<0><<<dim3(32, 24), 256, 0, stream>>>(
        xb, wqkvb, nullptr, qkvb, nullptr, 4096, 3072, 1024);

    qkv_norm_kernel<<<4096, 256, 0, stream>>>(qkvb, q_bias, v_bias, scale_mul, Qw, Kw, Vw);

    bias_prep_kernel<<<2048, 256, 0, stream>>>(attn_bias, bias_bf);
    v_transpose_kernel<<<dim3(32, 32), 256, 0, stream>>>(Vw, Vt);

    attn_kernel<<<dim3(32, 16), 256, 0, stream>>>(Qw, Kw, Vt, bias_bf, scale_mul, Oc);

    gemm_bt_kernel<1><<<dim3(32, 8), 256, 0, stream>>>(
        Oc, wprojb, out, nullptr, b_proj, 4096, 1024, 1024);
}

// Round 8
// 197.677 us; speedup vs baseline: 1.9435x; 1.0590x over previous
//
#include <hip/hip_runtime.h>

// Pipeline: cvt(x,Wqkv,Wproj) -> GEMM qkv(bf16, m97 gload_lds, XCD-swz) -> norm/split
//           (Q pre-scaled smh*log2e) -> bias_prep (bias*log2e) -> v_transpose ->
//           flash attn (QBLK=64, swapped-QK^T, bias-in-acc, k-permuted in-register P,
//                       reg-staged dbuf K/V, 1 barrier/iter) -> GEMM proj(f32+bias, XCD-swz)
// B=2 L=2048 C=1024 H=16 D=64. All matmuls bf16 MFMA 16x16x32, f32 accumulate.

typedef __bf16 bf16x8 __attribute__((ext_vector_type(8)));
typedef __bf16 bf16x4 __attribute__((ext_vector_type(4)));
typedef float  f32x4  __attribute__((ext_vector_type(4)));

#define BB 2
#define LL 2048
#define CC 1024
#define HH 16
#define DD 64
#define LOG2E 1.44269504088896f

__device__ __forceinline__ f32x4 mfma_16x16x32(bf16x8 a, bf16x8 b, f32x4 c) {
    return __builtin_amdgcn_mfma_f32_16x16x32_bf16(a, b, c, 0, 0, 0);
}

// async global->LDS, 16B per lane; LDS dest = wave-uniform base + lane*16
__device__ __forceinline__ void gload_lds16(const __bf16* g, __bf16* lds) {
    __builtin_amdgcn_global_load_lds(
        (const __attribute__((address_space(1))) unsigned int*)g,
        (__attribute__((address_space(3))) unsigned int*)lds,
        16, 0, 0);
}

__device__ __forceinline__ unsigned pk_bf16(float a, float b) {
    unsigned short ua = __builtin_bit_cast(unsigned short, (__bf16)a);
    unsigned short ub = __builtin_bit_cast(unsigned short, (__bf16)b);
    return (unsigned)ua | ((unsigned)ub << 16);
}

// ---------------- f32 -> bf16 convert ----------------
__global__ __launch_bounds__(256) void cvt_bf16_kernel(const float* __restrict__ in,
                                                       __bf16* __restrict__ out, int n4) {
    int i = blockIdx.x * 256 + threadIdx.x;
    if (i >= n4) return;
    float4 v = reinterpret_cast<const float4*>(in)[i];
    bf16x4 o;
    o[0] = (__bf16)v.x; o[1] = (__bf16)v.y; o[2] = (__bf16)v.z; o[3] = (__bf16)v.w;
    reinterpret_cast<bf16x4*>(out)[i] = o;
}

// ---------------- bias prep: rowmax + bf16((bias - rowmax)*log2e) ----------------
__global__ __launch_bounds__(256) void bias_prep_kernel(const float* __restrict__ bias,
                                                        __bf16* __restrict__ bias_bf) {
    __shared__ float wmax[4];
    const int l = blockIdx.x, tid = threadIdx.x;
    const int w = tid >> 6;
    float4 a = reinterpret_cast<const float4*>(bias + (size_t)l * 2048)[tid];
    float4 b = reinterpret_cast<const float4*>(bias + (size_t)l * 2048 + 1024)[tid];
    float m = fmaxf(fmaxf(fmaxf(a.x, a.y), fmaxf(a.z, a.w)),
                    fmaxf(fmaxf(b.x, b.y), fmaxf(b.z, b.w)));
#pragma unroll
    for (int off = 1; off < 64; off <<= 1) m = fmaxf(m, __shfl_xor(m, off, 64));
    if ((tid & 63) == 0) wmax[w] = m;
    __syncthreads();
    float M = fmaxf(fmaxf(wmax[0], wmax[1]), fmaxf(wmax[2], wmax[3]));
    bf16x4 o0, o1;
    o0[0] = (__bf16)((a.x - M) * LOG2E); o0[1] = (__bf16)((a.y - M) * LOG2E);
    o0[2] = (__bf16)((a.z - M) * LOG2E); o0[3] = (__bf16)((a.w - M) * LOG2E);
    o1[0] = (__bf16)((b.x - M) * LOG2E); o1[1] = (__bf16)((b.y - M) * LOG2E);
    o1[2] = (__bf16)((b.z - M) * LOG2E); o1[3] = (__bf16)((b.w - M) * LOG2E);
    reinterpret_cast<bf16x4*>(bias_bf + (size_t)l * 2048)[tid] = o0;
    reinterpret_cast<bf16x4*>(bias_bf + (size_t)l * 2048 + 1024)[tid] = o1;
}

// ---------------- GEMM: C[M,N] = A[M,K] * B[N,K]^T (+bias), m97 + XCD swizzle -------------
template <int OUT_MODE>
__global__ __launch_bounds__(256) void gemm_bt_kernel(
    const __bf16* __restrict__ A, const __bf16* __restrict__ Bm,
    float* __restrict__ Cf, __bf16* __restrict__ Cb,
    const float* __restrict__ bias, int M, int N, int K) {
    __shared__ __bf16 As[128 * 64];   // LDS[row][c] = A[row][c ^ ((row&7)<<4)]  (byte view)
    __shared__ __bf16 Bs[128 * 64];
    const int tid = threadIdx.x;
    // bijective XCD swizzle (nwg % 8 == 0 for both call sites)
    const int nwg = gridDim.x * gridDim.y;
    const int flat = blockIdx.y * gridDim.x + blockIdx.x;
    const int wg = (flat & 7) * (nwg >> 3) + (flat >> 3);
    const int m0 = (wg % gridDim.x) * 128, n0 = (wg / gridDim.x) * 128;
    const int w  = tid >> 6, l = tid & 63;
    const int wr = (w >> 1) * 64, wc = (w & 1) * 64;
    const int lr = l & 15, lg = l >> 4;
    const int rmask = (lr & 7) << 4;
    f32x4 acc[4][4] = {};
    const int lrow = l >> 3;                      // 0..7
    const int celem = (((l & 7) ^ lrow) << 3);    // pre-swizzled col (elements)

    for (int kt = 0; kt < K; kt += 64) {
        __syncthreads();
#pragma unroll
        for (int i = 0; i < 4; ++i) {
            const int row = w * 32 + i * 8;
            gload_lds16(A + (size_t)(m0 + row + lrow) * K + kt + celem, &As[row * 64]);
            gload_lds16(Bm + (size_t)(n0 + row + lrow) * K + kt + celem, &Bs[row * 64]);
        }
        asm volatile("s_waitcnt vmcnt(0)" ::: "memory");
        __syncthreads();
#pragma unroll
        for (int kk = 0; kk < 2; ++kk) {          // kk*64 bytes
            bf16x8 af[4], bfr[4];
#pragma unroll
            for (int m = 0; m < 4; ++m)
                af[m] = *reinterpret_cast<const bf16x8*>(
                    (char*)As + (wr + m * 16 + lr) * 128 + ((kk * 64 + lg * 16) ^ rmask));
#pragma unroll
            for (int n = 0; n < 4; ++n)
                bfr[n] = *reinterpret_cast<const bf16x8*>(
                    (char*)Bs + (wc + n * 16 + lr) * 128 + ((kk * 64 + lg * 16) ^ rmask));
#pragma unroll
            for (int m = 0; m < 4; ++m)
#pragma unroll
                for (int n = 0; n < 4; ++n)
                    acc[m][n] = mfma_16x16x32(af[m], bfr[n], acc[m][n]);
        }
    }
#pragma unroll
    for (int m = 0; m < 4; ++m) {
#pragma unroll
        for (int n = 0; n < 4; ++n) {
            const int row = m0 + wr + m * 16 + lg * 4;
            const int col = n0 + wc + n * 16 + lr;
#pragma unroll
            for (int r = 0; r < 4; ++r) {
                float v = acc[m][n][r];
                if (OUT_MODE == 0) {
                    Cb[(size_t)(row + r) * N + col] = (__bf16)v;
                } else {
                    Cf[(size_t)(row + r) * N + col] = v + bias[col];
                }
            }
        }
    }
}

// ---------------- bias add + l2norm + scale, split into Q/K/V (B,H,L,D) bf16 ----------------
// Q additionally pre-scaled by log2e so the attn exponent is exp2-ready.
__global__ __launch_bounds__(256) void qkv_norm_kernel(
    const __bf16* __restrict__ qkv, const float* __restrict__ q_bias,
    const float* __restrict__ v_bias, const float* __restrict__ scale_mul,
    __bf16* __restrict__ Q, __bf16* __restrict__ K, __bf16* __restrict__ V) {
    const int bl = blockIdx.x;
    const int tid = threadIdx.x;
    const int w = tid >> 6, d = tid & 63;
    const int b = bl >> 11, l = bl & 2047;
    for (int g = w; g < 48; g += 4) {
        const int s = g >> 4, h = g & 15;
        float v = (float)qkv[(size_t)bl * 3072 + g * 64 + d];
        if (s == 0) v += q_bias[h * 64 + d];
        if (s == 2) v += v_bias[h * 64 + d];
        if (s < 2) {
            float ss = v * v;
#pragma unroll
            for (int off = 1; off < 64; off <<= 1) ss += __shfl_xor(ss, off, 64);
            float nrm = sqrtf(ss);
            v = v / fmaxf(nrm, 1e-12f);
            if (s == 0) v *= __expf(fminf(scale_mul[h], 4.60517019f)) * LOG2E;
        }
        __bf16* dst = (s == 0) ? Q : ((s == 1) ? K : V);
        dst[((size_t)(b * 16 + h) * 2048 + l) * 64 + d] = (__bf16)v;
    }
}

// ---------------- V transpose: (B,H,L,D) -> (B,H,D,L) ----------------
__global__ __launch_bounds__(256) void v_transpose_kernel(const __bf16* __restrict__ Vin,
                                                          __bf16* __restrict__ Vt) {
    __shared__ __bf16 T[64][72];
    const int lb = blockIdx.x, bh = blockIdx.y;
    const int tid = threadIdx.x;
    const size_t base = (size_t)bh * LL * DD;
    const int row = tid >> 2, c = (tid & 3) * 16;
    {
        const __bf16* src = Vin + base + (size_t)(lb * 64 + row) * 64 + c;
        *reinterpret_cast<bf16x8*>(&T[row][c])     = *reinterpret_cast<const bf16x8*>(src);
        *reinterpret_cast<bf16x8*>(&T[row][c + 8]) = *reinterpret_cast<const bf16x8*>(src + 8);
    }
    __syncthreads();
    bf16x8 o0, o1;
#pragma unroll
    for (int j = 0; j < 8; ++j) {
        o0[j] = T[c + j][row];
        o1[j] = T[c + 8 + j][row];
    }
    __bf16* dst = Vt + base + (size_t)row * 2048 + lb * 64 + c;
    *reinterpret_cast<bf16x8*>(dst)     = o0;
    *reinterpret_cast<bf16x8*>(dst + 8) = o1;
}

// ---------------- flash attention: R4 structure + in-register P (k-permutation) ----------
// grid (bh=32, qb=32); 256 threads = 4 waves; wave w owns q-rows [qb*64+w*16, +16).
// Swapped QK^T: lane(lr,lg) holds P[q=lr][k=16t+4lg+r]. k-permutation
// pi(16t+4lg+r)=32*(t>=2)+8lg+4*(t&1)+r makes lane's own values its A-operand slots;
// V's compensating permutation is folded into the vf read addressing (b64 reads).
__global__ __launch_bounds__(256, 4) void attn_kernel(
    const __bf16* __restrict__ Q, const __bf16* __restrict__ K,
    const __bf16* __restrict__ Vt, const __bf16* __restrict__ biasL,
    const float* __restrict__ scale_mul, __bf16* __restrict__ Octx) {
    __shared__ __bf16 KVs[2][2][64 * 64];   // [buf][K/V]; LDS[row][c]=G[row][c^((row&7)<<4)]
    const int bh = blockIdx.x, qb = blockIdx.y;
    const int tid = threadIdx.x;
    const int w = tid >> 6, l = tid & 63;
    const int lr = l & 15, lg = l >> 4;
    const int rmask = (lr & 7) << 4;
    const int b = bh >> 4, h = bh & 15;
    const size_t base = (size_t)bh * LL * DD;
    const float smh = __expf(fminf(scale_mul[h], 4.60517019f));
    const float cexp = -smh * LOG2E;

    const int gq = qb * 64 + w * 16 + lr;   // this lane's q row
    bf16x8 qf[2];
    qf[0] = *reinterpret_cast<const bf16x8*>(Q + base + (size_t)gq * 64 + lg * 8);
    qf[1] = *reinterpret_cast<const bf16x8*>(Q + base + (size_t)gq * 64 + 32 + lg * 8);
    const __bf16* brow = biasL + (size_t)gq * 2048 + lg * 4;

    // staging geometry: 4 threads per row, 32B chunks (reg-staged, issue-early/write-late)
    const int srow = tid >> 2;
    const int scb  = (tid & 3) * 32;               // byte col base
    const int smask = (srow & 7) << 4;
    const __bf16* kgbase = K  + base + (size_t)srow * 64   + (tid & 3) * 16;
    const __bf16* vgbase = Vt + base + (size_t)srow * 2048 + (tid & 3) * 16;

    bf16x8 k0, k1, v0, v1;
    auto stage_regs = [&](int kb) {
        const __bf16* kg = kgbase + (size_t)kb * 64 * 64;
        k0 = *reinterpret_cast<const bf16x8*>(kg);
        k1 = *reinterpret_cast<const bf16x8*>(kg + 8);
        const __bf16* vg = vgbase + kb * 64;
        v0 = *reinterpret_cast<const bf16x8*>(vg);
        v1 = *reinterpret_cast<const bf16x8*>(vg + 8);
    };
    auto write_lds = [&](int buf) {
        char* kp = (char*)KVs[buf][0] + srow * 128;
        char* vp = (char*)KVs[buf][1] + srow * 128;
        *reinterpret_cast<bf16x8*>(kp + (scb ^ smask))        = k0;
        *reinterpret_cast<bf16x8*>(kp + ((scb + 16) ^ smask)) = k1;
        *reinterpret_cast<bf16x8*>(vp + (scb ^ smask))        = v0;
        *reinterpret_cast<bf16x8*>(vp + ((scb + 16) ^ smask)) = v1;
    };

    stage_regs(0);
    write_lds(0);

    f32x4 Oa[4] = {};
    float lsum = 0.f;
    int cur = 0;

    bf16x4 bcur[4];
#pragma unroll
    for (int t = 0; t < 4; ++t)
        bcur[t] = *reinterpret_cast<const bf16x4*>(brow + t * 16);

    for (int kb = 0; kb < 32; ++kb) {
        __syncthreads();                    // buf[cur] published; buf[cur^1] free
        if (kb < 31) stage_regs(kb + 1);    // issue next-tile global loads early (T14)

        bf16x4 bnext[4];
        if (kb < 31) {
#pragma unroll
            for (int t = 0; t < 4; ++t)
                bnext[t] = *reinterpret_cast<const bf16x4*>(brow + (kb + 1) * 64 + t * 16);
        }

        const char* Kc = (const char*)KVs[cur][0];
        const char* Vc = (const char*)KVs[cur][1];

        // acc init = bias*log2e + cexp  (bias folded into MFMA C-input)
        f32x4 sa[4];
#pragma unroll
        for (int t = 0; t < 4; ++t)
#pragma unroll
            for (int r = 0; r < 4; ++r)
                sa[t][r] = (float)bcur[t][r] + cexp;

        // S^T·log2e : lane holds q=lr, k = 16t+4lg+r
#pragma unroll
        for (int t = 0; t < 4; ++t) {
            const char* kr = Kc + (t * 16 + lr) * 128;
            bf16x8 kf0 = *reinterpret_cast<const bf16x8*>(kr + ((lg * 16) ^ rmask));
            bf16x8 kf1 = *reinterpret_cast<const bf16x8*>(kr + ((64 + lg * 16) ^ rmask));
            sa[t] = mfma_16x16x32(kf0, qf[0], sa[t]);
            sa[t] = mfma_16x16x32(kf1, qf[1], sa[t]);
        }

        // softmax: p = exp2(sa); pack lane-local values straight into A-operand slots
        float p[4][4];
#pragma unroll
        for (int t = 0; t < 4; ++t)
#pragma unroll
            for (int r = 0; r < 4; ++r) {
                p[t][r] = exp2f(sa[t][r]);
                lsum += p[t][r];
            }
        union Upa { unsigned u[4]; bf16x8 v; } pa0, pa1;
        pa0.u[0] = pk_bf16(p[0][0], p[0][1]); pa0.u[1] = pk_bf16(p[0][2], p[0][3]);
        pa0.u[2] = pk_bf16(p[1][0], p[1][1]); pa0.u[3] = pk_bf16(p[1][2], p[1][3]);
        pa1.u[0] = pk_bf16(p[2][0], p[2][1]); pa1.u[1] = pk_bf16(p[2][2], p[2][3]);
        pa1.u[2] = pk_bf16(p[3][0], p[3][1]); pa1.u[3] = pk_bf16(p[3][2], p[3][3]);

        // O += P·V with permuted k-rows: vf slot j=4u+r (frag c) <- Vs[d][32c+16u+4lg+r]
#pragma unroll
        for (int t = 0; t < 4; ++t) {
            const char* vr = Vc + (t * 16 + lr) * 128;
            union Uv { uint2 d[2]; bf16x8 v; } vf0, vf1;
            vf0.d[0] = *reinterpret_cast<const uint2*>(vr + ((lg * 8) ^ rmask));
            vf0.d[1] = *reinterpret_cast<const uint2*>(vr + ((32 + lg * 8) ^ rmask));
            vf1.d[0] = *reinterpret_cast<const uint2*>(vr + ((64 + lg * 8) ^ rmask));
            vf1.d[1] = *reinterpret_cast<const uint2*>(vr + ((96 + lg * 8) ^ rmask));
            Oa[t] = mfma_16x16x32(pa0.v, vf0.v, Oa[t]);
            Oa[t] = mfma_16x16x32(pa1.v, vf1.v, Oa[t]);
        }

        if (kb < 31) {
            write_lds(cur ^ 1);             // write-late; dep on loads forces vmcnt
#pragma unroll
            for (int t = 0; t < 4; ++t) bcur[t] = bnext[t];
        }
        cur ^= 1;
    }

    // reduce lsum: partials for q=lr live at lanes lr, lr+16, lr+32, lr+48
    lsum += __shfl_xor(lsum, 16, 64);
    lsum += __shfl_xor(lsum, 32, 64);
    float inv[4];
#pragma unroll
    for (int r = 0; r < 4; ++r) inv[r] = 1.0f / __shfl(lsum, lg * 4 + r, 64);

#pragma unroll
    for (int t = 0; t < 4; ++t)
#pragma unroll
        for (int r = 0; r < 4; ++r) {
            const int row = qb * 64 + w * 16 + lg * 4 + r;
            float o = Oa[t][r] * inv[r];
            Octx[((size_t)(b * 2048 + row)) * 1024 + h * 64 + t * 16 + lr] = (__bf16)o;
        }
}

// ---------------- launch ----------------
extern "C" void kernel_launch(void* const* d_in, const int* in_sizes, int n_in,
                              void* d_out, int out_size, void* d_ws, size_t ws_size,
                              hipStream_t stream) {
    const float* x         = (const float*)d_in[0];
    const float* attn_bias = (const float*)d_in[1];
    const float* W_qkv     = (const float*)d_in[2];
    const float* q_bias    = (const float*)d_in[3];
    const float* v_bias    = (const float*)d_in[4];
    const float* scale_mul = (const float*)d_in[5];
    const float* W_proj    = (const float*)d_in[6];
    const float* b_proj    = (const float*)d_in[7];
    float* out = (float*)d_out;

    char* ws = (char*)d_ws;
    size_t off = 0;
    auto alloc = [&](size_t bytes) {
        void* p = ws + off;
        off = (off + bytes + 255) & ~(size_t)255;
        return p;
    };
    __bf16* xb     = (__bf16*)alloc((size_t)4096 * 1024 * 2);
    __bf16* wqkvb  = (__bf16*)alloc((size_t)3072 * 1024 * 2);
    __bf16* wprojb = (__bf16*)alloc((size_t)1024 * 1024 * 2);
    __bf16* qkvb   = (__bf16*)alloc((size_t)4096 * 3072 * 2);   // 24 MB
    __bf16* Qw     = (__bf16*)alloc((size_t)BB * HH * LL * DD * 2);
    __bf16* Kw     = (__bf16*)alloc((size_t)BB * HH * LL * DD * 2);
    __bf16* Vw     = (__bf16*)alloc((size_t)BB * HH * LL * DD * 2);
    __bf16* Oc     = (__bf16*)alloc((size_t)4096 * 1024 * 2);
    // alias: after qkv_norm consumes qkvb, reuse its space for bias_bf and Vt
    __bf16* bias_bf = qkvb;                                      // 8 MB
    __bf16* Vt      = qkvb + (size_t)2048 * 2048;                // 8 MB

    cvt_bf16_kernel<<<4096, 256, 0, stream>>>(x, xb, 4096 * 1024 / 4);
    cvt_bf16_kernel<<<3072, 256, 0, stream>>>(W_qkv, wqkvb, 3072 * 1024 / 4);
    cvt_bf16_kernel<<<1024, 256, 0, stream>>>(W_proj, wprojb, 1024 * 1024 / 4);

    gemm_bt_kernel<0><<<dim3(32, 24), 256, 0, stream>>>(
        xb, wqkvb, nullptr, qkvb, nullptr, 4096, 3072, 1024);

    qkv_norm_kernel<<<4096, 256, 0, stream>>>(qkvb, q_bias, v_bias, scale_mul, Qw, Kw, Vw);

    bias_prep_kernel<<<2048, 256, 0, stream>>>(attn_bias, bias_bf);
    v_transpose_kernel<<<dim3(32, 32), 256, 0, stream>>>(Vw, Vt);

    attn_kernel<<<dim3(32, 32), 256, 0, stream>>>(Qw, Kw, Vt, bias_bf, scale_mul, Oc);

    gemm_bt_kernel<1><<<dim3(32, 8), 256, 0, stream>>>(
        Oc, wprojb, out, nullptr, b_proj, 4096, 1024, 1024);
}

// Round 9
// 187.119 us; speedup vs baseline: 2.0531x; 1.0564x over previous
//
#include <hip/hip_runtime.h>

// Pipeline: cvt(x,Wqkv,Wproj) -> GEMM qkv + fused bias/l2norm/scale/split (Q pre-scaled
//           smh*log2e) -> bias_prep (bias*log2e) -> v_transpose ->
//           flash attn (QBLK=64, swapped-QK^T, bias-in-acc, in-register P, dbuf, setprio)
//           -> GEMM proj(f32+bias, XCD-swz)
// B=2 L=2048 C=1024 H=16 D=64. All matmuls bf16 MFMA 16x16x32, f32 accumulate.

typedef __bf16 bf16x8 __attribute__((ext_vector_type(8)));
typedef __bf16 bf16x4 __attribute__((ext_vector_type(4)));
typedef float  f32x4  __attribute__((ext_vector_type(4)));

#define BB 2
#define LL 2048
#define CC 1024
#define HH 16
#define DD 64
#define LOG2E 1.44269504088896f

__device__ __forceinline__ f32x4 mfma_16x16x32(bf16x8 a, bf16x8 b, f32x4 c) {
    return __builtin_amdgcn_mfma_f32_16x16x32_bf16(a, b, c, 0, 0, 0);
}

// async global->LDS, 16B per lane; LDS dest = wave-uniform base + lane*16
__device__ __forceinline__ void gload_lds16(const __bf16* g, __bf16* lds) {
    __builtin_amdgcn_global_load_lds(
        (const __attribute__((address_space(1))) unsigned int*)g,
        (__attribute__((address_space(3))) unsigned int*)lds,
        16, 0, 0);
}

__device__ __forceinline__ unsigned pk_bf16(float a, float b) {
    unsigned short ua = __builtin_bit_cast(unsigned short, (__bf16)a);
    unsigned short ub = __builtin_bit_cast(unsigned short, (__bf16)b);
    return (unsigned)ua | ((unsigned)ub << 16);
}

// ---------------- f32 -> bf16 convert ----------------
__global__ __launch_bounds__(256) void cvt_bf16_kernel(const float* __restrict__ in,
                                                       __bf16* __restrict__ out, int n4) {
    int i = blockIdx.x * 256 + threadIdx.x;
    if (i >= n4) return;
    float4 v = reinterpret_cast<const float4*>(in)[i];
    bf16x4 o;
    o[0] = (__bf16)v.x; o[1] = (__bf16)v.y; o[2] = (__bf16)v.z; o[3] = (__bf16)v.w;
    reinterpret_cast<bf16x4*>(out)[i] = o;
}

// ---------------- bias prep: rowmax + bf16((bias - rowmax)*log2e) ----------------
__global__ __launch_bounds__(256) void bias_prep_kernel(const float* __restrict__ bias,
                                                        __bf16* __restrict__ bias_bf) {
    __shared__ float wmax[4];
    const int l = blockIdx.x, tid = threadIdx.x;
    const int w = tid >> 6;
    float4 a = reinterpret_cast<const float4*>(bias + (size_t)l * 2048)[tid];
    float4 b = reinterpret_cast<const float4*>(bias + (size_t)l * 2048 + 1024)[tid];
    float m = fmaxf(fmaxf(fmaxf(a.x, a.y), fmaxf(a.z, a.w)),
                    fmaxf(fmaxf(b.x, b.y), fmaxf(b.z, b.w)));
#pragma unroll
    for (int off = 1; off < 64; off <<= 1) m = fmaxf(m, __shfl_xor(m, off, 64));
    if ((tid & 63) == 0) wmax[w] = m;
    __syncthreads();
    float M = fmaxf(fmaxf(wmax[0], wmax[1]), fmaxf(wmax[2], wmax[3]));
    bf16x4 o0, o1;
    o0[0] = (__bf16)((a.x - M) * LOG2E); o0[1] = (__bf16)((a.y - M) * LOG2E);
    o0[2] = (__bf16)((a.z - M) * LOG2E); o0[3] = (__bf16)((a.w - M) * LOG2E);
    o1[0] = (__bf16)((b.x - M) * LOG2E); o1[1] = (__bf16)((b.y - M) * LOG2E);
    o1[2] = (__bf16)((b.z - M) * LOG2E); o1[3] = (__bf16)((b.w - M) * LOG2E);
    reinterpret_cast<bf16x4*>(bias_bf + (size_t)l * 2048)[tid] = o0;
    reinterpret_cast<bf16x4*>(bias_bf + (size_t)l * 2048 + 1024)[tid] = o1;
}

// ---------------- QKV GEMM + fused bias/l2norm/scale/split ----------------
// C = x(M=4096,K=1024) * Wqkv^T(N=3072); each wave's 64-col sub-tile = exactly one head
// of one type (q/k/v). Epilogue: +bias, l2norm over d (4 in-lane + 16-lane shfl tree),
// q *= exp(min(scale_mul,log100))*log2e, write to Q/K/V in (B,H,L,D) bf16.
__global__ __launch_bounds__(256) void gemm_qkv_fused_kernel(
    const __bf16* __restrict__ A, const __bf16* __restrict__ Bm,
    const float* __restrict__ q_bias, const float* __restrict__ v_bias,
    const float* __restrict__ scale_mul,
    __bf16* __restrict__ Qw, __bf16* __restrict__ Kw, __bf16* __restrict__ Vw) {
    __shared__ __bf16 As[128 * 64];   // LDS[row][c] = A[row][c ^ ((row&7)<<4)]  (byte view)
    __shared__ __bf16 Bs[128 * 64];
    const int tid = threadIdx.x;
    const int K = 1024;
    // bijective XCD swizzle (nwg = 768, %8==0)
    const int nwg = gridDim.x * gridDim.y;
    const int flat = blockIdx.y * gridDim.x + blockIdx.x;
    const int wg = (flat & 7) * (nwg >> 3) + (flat >> 3);
    const int m0 = (wg % gridDim.x) * 128, n0 = (wg / gridDim.x) * 128;
    const int w  = tid >> 6, l = tid & 63;
    const int wr = (w >> 1) * 64, wc = (w & 1) * 64;
    const int lr = l & 15, lg = l >> 4;
    const int rmask = (lr & 7) << 4;
    f32x4 acc[4][4] = {};
    const int lrow = l >> 3;
    const int celem = (((l & 7) ^ lrow) << 3);

    for (int kt = 0; kt < K; kt += 64) {
        __syncthreads();
#pragma unroll
        for (int i = 0; i < 4; ++i) {
            const int row = w * 32 + i * 8;
            gload_lds16(A + (size_t)(m0 + row + lrow) * K + kt + celem, &As[row * 64]);
            gload_lds16(Bm + (size_t)(n0 + row + lrow) * K + kt + celem, &Bs[row * 64]);
        }
        asm volatile("s_waitcnt vmcnt(0)" ::: "memory");
        __syncthreads();
#pragma unroll
        for (int kk = 0; kk < 2; ++kk) {
            bf16x8 af[4], bfr[4];
#pragma unroll
            for (int m = 0; m < 4; ++m)
                af[m] = *reinterpret_cast<const bf16x8*>(
                    (char*)As + (wr + m * 16 + lr) * 128 + ((kk * 64 + lg * 16) ^ rmask));
#pragma unroll
            for (int n = 0; n < 4; ++n)
                bfr[n] = *reinterpret_cast<const bf16x8*>(
                    (char*)Bs + (wc + n * 16 + lr) * 128 + ((kk * 64 + lg * 16) ^ rmask));
#pragma unroll
            for (int m = 0; m < 4; ++m)
#pragma unroll
                for (int n = 0; n < 4; ++n)
                    acc[m][n] = mfma_16x16x32(af[m], bfr[n], acc[m][n]);
        }
    }

    // ---- fused epilogue ----
    const int gcbase = n0 + wc;              // wave-uniform; covers cols gcbase..gcbase+63
    const int type = gcbase >> 10;           // 0=q, 1=k, 2=v
    const int h = (gcbase & 1023) >> 6;      // wave-uniform head
    float qscale = 1.0f;
    if (type == 0) qscale = __expf(fminf(scale_mul[h], 4.60517019f)) * LOG2E;
    __bf16* dst = (type == 0) ? Qw : (type == 1) ? Kw : Vw;

#pragma unroll
    for (int m = 0; m < 4; ++m) {
        if (type != 1) {                     // q/v bias (k has zero bias)
            const float* bptr = (type == 0) ? q_bias : v_bias;
#pragma unroll
            for (int n = 0; n < 4; ++n) {
                float bv = bptr[(gcbase & 1023) + n * 16 + lr];
#pragma unroll
                for (int r = 0; r < 4; ++r) acc[m][n][r] += bv;
            }
        }
        float rs[4];
        if (type < 2) {
#pragma unroll
            for (int r = 0; r < 4; ++r) {
                float ss = 0.f;
#pragma unroll
                for (int n = 0; n < 4; ++n) ss += acc[m][n][r] * acc[m][n][r];
                rs[r] = ss;
            }
#pragma unroll
            for (int off = 1; off < 16; off <<= 1)
#pragma unroll
                for (int r = 0; r < 4; ++r) rs[r] += __shfl_xor(rs[r], off, 64);
#pragma unroll
            for (int r = 0; r < 4; ++r)
                rs[r] = ((type == 0) ? qscale : 1.0f) / fmaxf(sqrtf(rs[r]), 1e-12f);
        } else {
#pragma unroll
            for (int r = 0; r < 4; ++r) rs[r] = 1.0f;
        }
        const int rowg = m0 + wr + m * 16 + lg * 4;
#pragma unroll
        for (int n = 0; n < 4; ++n) {
            const int d = n * 16 + lr;
#pragma unroll
            for (int r = 0; r < 4; ++r) {
                const int row = rowg + r;
                const int bb = row >> 11, ll = row & 2047;
                dst[((size_t)((bb << 4) + h) * 2048 + ll) * 64 + d] =
                    (__bf16)(acc[m][n][r] * rs[r]);
            }
        }
    }
}

// ---------------- GEMM: C[M,N] = A[M,K]*B[N,K]^T + bias (f32 out), m97 + XCD swz ----------
__global__ __launch_bounds__(256) void gemm_proj_kernel(
    const __bf16* __restrict__ A, const __bf16* __restrict__ Bm,
    float* __restrict__ Cf, const float* __restrict__ bias, int M, int N, int K) {
    __shared__ __bf16 As[128 * 64];
    __shared__ __bf16 Bs[128 * 64];
    const int tid = threadIdx.x;
    const int nwg = gridDim.x * gridDim.y;
    const int flat = blockIdx.y * gridDim.x + blockIdx.x;
    const int wg = (flat & 7) * (nwg >> 3) + (flat >> 3);
    const int m0 = (wg % gridDim.x) * 128, n0 = (wg / gridDim.x) * 128;
    const int w  = tid >> 6, l = tid & 63;
    const int wr = (w >> 1) * 64, wc = (w & 1) * 64;
    const int lr = l & 15, lg = l >> 4;
    const int rmask = (lr & 7) << 4;
    f32x4 acc[4][4] = {};
    const int lrow = l >> 3;
    const int celem = (((l & 7) ^ lrow) << 3);

    for (int kt = 0; kt < K; kt += 64) {
        __syncthreads();
#pragma unroll
        for (int i = 0; i < 4; ++i) {
            const int row = w * 32 + i * 8;
            gload_lds16(A + (size_t)(m0 + row + lrow) * K + kt + celem, &As[row * 64]);
            gload_lds16(Bm + (size_t)(n0 + row + lrow) * K + kt + celem, &Bs[row * 64]);
        }
        asm volatile("s_waitcnt vmcnt(0)" ::: "memory");
        __syncthreads();
#pragma unroll
        for (int kk = 0; kk < 2; ++kk) {
            bf16x8 af[4], bfr[4];
#pragma unroll
            for (int m = 0; m < 4; ++m)
                af[m] = *reinterpret_cast<const bf16x8*>(
                    (char*)As + (wr + m * 16 + lr) * 128 + ((kk * 64 + lg * 16) ^ rmask));
#pragma unroll
            for (int n = 0; n < 4; ++n)
                bfr[n] = *reinterpret_cast<const bf16x8*>(
                    (char*)Bs + (wc + n * 16 + lr) * 128 + ((kk * 64 + lg * 16) ^ rmask));
#pragma unroll
            for (int m = 0; m < 4; ++m)
#pragma unroll
                for (int n = 0; n < 4; ++n)
                    acc[m][n] = mfma_16x16x32(af[m], bfr[n], acc[m][n]);
        }
    }
#pragma unroll
    for (int m = 0; m < 4; ++m)
#pragma unroll
        for (int n = 0; n < 4; ++n) {
            const int row = m0 + wr + m * 16 + lg * 4;
            const int col = n0 + wc + n * 16 + lr;
#pragma unroll
            for (int r = 0; r < 4; ++r)
                Cf[(size_t)(row + r) * N + col] = acc[m][n][r] + bias[col];
        }
}

// ---------------- V transpose: (B,H,L,D) -> (B,H,D,L) ----------------
__global__ __launch_bounds__(256) void v_transpose_kernel(const __bf16* __restrict__ Vin,
                                                          __bf16* __restrict__ Vt) {
    __shared__ __bf16 T[64][72];
    const int lb = blockIdx.x, bh = blockIdx.y;
    const int tid = threadIdx.x;
    const size_t base = (size_t)bh * LL * DD;
    const int row = tid >> 2, c = (tid & 3) * 16;
    {
        const __bf16* src = Vin + base + (size_t)(lb * 64 + row) * 64 + c;
        *reinterpret_cast<bf16x8*>(&T[row][c])     = *reinterpret_cast<const bf16x8*>(src);
        *reinterpret_cast<bf16x8*>(&T[row][c + 8]) = *reinterpret_cast<const bf16x8*>(src + 8);
    }
    __syncthreads();
    bf16x8 o0, o1;
#pragma unroll
    for (int j = 0; j < 8; ++j) {
        o0[j] = T[c + j][row];
        o1[j] = T[c + 8 + j][row];
    }
    __bf16* dst = Vt + base + (size_t)row * 2048 + lb * 64 + c;
    *reinterpret_cast<bf16x8*>(dst)     = o0;
    *reinterpret_cast<bf16x8*>(dst + 8) = o1;
}

// ---------------- flash attention: R8 structure + setprio around MFMA ----------
// grid (bh=32, qb=32); 256 threads = 4 waves; wave w owns q-rows [qb*64+w*16, +16).
__global__ __launch_bounds__(256, 4) void attn_kernel(
    const __bf16* __restrict__ Q, const __bf16* __restrict__ K,
    const __bf16* __restrict__ Vt, const __bf16* __restrict__ biasL,
    const float* __restrict__ scale_mul, __bf16* __restrict__ Octx) {
    __shared__ __bf16 KVs[2][2][64 * 64];   // [buf][K/V]; LDS[row][c]=G[row][c^((row&7)<<4)]
    const int bh = blockIdx.x, qb = blockIdx.y;
    const int tid = threadIdx.x;
    const int w = tid >> 6, l = tid & 63;
    const int lr = l & 15, lg = l >> 4;
    const int rmask = (lr & 7) << 4;
    const int b = bh >> 4, h = bh & 15;
    const size_t base = (size_t)bh * LL * DD;
    const float smh = __expf(fminf(scale_mul[h], 4.60517019f));
    const float cexp = -smh * LOG2E;

    const int gq = qb * 64 + w * 16 + lr;
    bf16x8 qf[2];
    qf[0] = *reinterpret_cast<const bf16x8*>(Q + base + (size_t)gq * 64 + lg * 8);
    qf[1] = *reinterpret_cast<const bf16x8*>(Q + base + (size_t)gq * 64 + 32 + lg * 8);
    const __bf16* brow = biasL + (size_t)gq * 2048 + lg * 4;

    const int srow = tid >> 2;
    const int scb  = (tid & 3) * 32;
    const int smask = (srow & 7) << 4;
    const __bf16* kgbase = K  + base + (size_t)srow * 64   + (tid & 3) * 16;
    const __bf16* vgbase = Vt + base + (size_t)srow * 2048 + (tid & 3) * 16;

    bf16x8 k0, k1, v0, v1;
    auto stage_regs = [&](int kb) {
        const __bf16* kg = kgbase + (size_t)kb * 64 * 64;
        k0 = *reinterpret_cast<const bf16x8*>(kg);
        k1 = *reinterpret_cast<const bf16x8*>(kg + 8);
        const __bf16* vg = vgbase + kb * 64;
        v0 = *reinterpret_cast<const bf16x8*>(vg);
        v1 = *reinterpret_cast<const bf16x8*>(vg + 8);
    };
    auto write_lds = [&](int buf) {
        char* kp = (char*)KVs[buf][0] + srow * 128;
        char* vp = (char*)KVs[buf][1] + srow * 128;
        *reinterpret_cast<bf16x8*>(kp + (scb ^ smask))        = k0;
        *reinterpret_cast<bf16x8*>(kp + ((scb + 16) ^ smask)) = k1;
        *reinterpret_cast<bf16x8*>(vp + (scb ^ smask))        = v0;
        *reinterpret_cast<bf16x8*>(vp + ((scb + 16) ^ smask)) = v1;
    };

    stage_regs(0);
    write_lds(0);

    f32x4 Oa[4] = {};
    float lsum = 0.f;
    int cur = 0;

    bf16x4 bcur[4];
#pragma unroll
    for (int t = 0; t < 4; ++t)
        bcur[t] = *reinterpret_cast<const bf16x4*>(brow + t * 16);

    for (int kb = 0; kb < 32; ++kb) {
        __syncthreads();
        if (kb < 31) stage_regs(kb + 1);

        bf16x4 bnext[4];
        if (kb < 31) {
#pragma unroll
            for (int t = 0; t < 4; ++t)
                bnext[t] = *reinterpret_cast<const bf16x4*>(brow + (kb + 1) * 64 + t * 16);
        }

        const char* Kc = (const char*)KVs[cur][0];
        const char* Vc = (const char*)KVs[cur][1];

        // acc init = bias*log2e + cexp
        f32x4 sa[4];
#pragma unroll
        for (int t = 0; t < 4; ++t)
#pragma unroll
            for (int r = 0; r < 4; ++r)
                sa[t][r] = (float)bcur[t][r] + cexp;

        // S^T·log2e : lane holds q=lr, k = 16t+4lg+r
        __builtin_amdgcn_s_setprio(1);
#pragma unroll
        for (int t = 0; t < 4; ++t) {
            const char* kr = Kc + (t * 16 + lr) * 128;
            bf16x8 kf0 = *reinterpret_cast<const bf16x8*>(kr + ((lg * 16) ^ rmask));
            bf16x8 kf1 = *reinterpret_cast<const bf16x8*>(kr + ((64 + lg * 16) ^ rmask));
            sa[t] = mfma_16x16x32(kf0, qf[0], sa[t]);
            sa[t] = mfma_16x16x32(kf1, qf[1], sa[t]);
        }
        __builtin_amdgcn_s_setprio(0);

        // softmax: p = exp2(sa); pack lane-local values into A-operand slots
        float p[4][4];
#pragma unroll
        for (int t = 0; t < 4; ++t)
#pragma unroll
            for (int r = 0; r < 4; ++r) {
                p[t][r] = exp2f(sa[t][r]);
                lsum += p[t][r];
            }
        union Upa { unsigned u[4]; bf16x8 v; } pa0, pa1;
        pa0.u[0] = pk_bf16(p[0][0], p[0][1]); pa0.u[1] = pk_bf16(p[0][2], p[0][3]);
        pa0.u[2] = pk_bf16(p[1][0], p[1][1]); pa0.u[3] = pk_bf16(p[1][2], p[1][3]);
        pa1.u[0] = pk_bf16(p[2][0], p[2][1]); pa1.u[1] = pk_bf16(p[2][2], p[2][3]);
        pa1.u[2] = pk_bf16(p[3][0], p[3][1]); pa1.u[3] = pk_bf16(p[3][2], p[3][3]);

        // O += P·V with permuted k-rows folded into vf addressing (b64 reads)
        __builtin_amdgcn_s_setprio(1);
#pragma unroll
        for (int t = 0; t < 4; ++t) {
            const char* vr = Vc + (t * 16 + lr) * 128;
            union Uv { uint2 d[2]; bf16x8 v; } vf0, vf1;
            vf0.d[0] = *reinterpret_cast<const uint2*>(vr + ((lg * 8) ^ rmask));
            vf0.d[1] = *reinterpret_cast<const uint2*>(vr + ((32 + lg * 8) ^ rmask));
            vf1.d[0] = *reinterpret_cast<const uint2*>(vr + ((64 + lg * 8) ^ rmask));
            vf1.d[1] = *reinterpret_cast<const uint2*>(vr + ((96 + lg * 8) ^ rmask));
            Oa[t] = mfma_16x16x32(pa0.v, vf0.v, Oa[t]);
            Oa[t] = mfma_16x16x32(pa1.v, vf1.v, Oa[t]);
        }
        __builtin_amdgcn_s_setprio(0);

        if (kb < 31) {
            write_lds(cur ^ 1);
#pragma unroll
            for (int t = 0; t < 4; ++t) bcur[t] = bnext[t];
        }
        cur ^= 1;
    }

    // reduce lsum: partials for q=lr live at lanes lr, lr+16, lr+32, lr+48
    lsum += __shfl_xor(lsum, 16, 64);
    lsum += __shfl_xor(lsum, 32, 64);
    float inv[4];
#pragma unroll
    for (int r = 0; r < 4; ++r) inv[r] = 1.0f / __shfl(lsum, lg * 4 + r, 64);

#pragma unroll
    for (int t = 0; t < 4; ++t)
#pragma unroll
        for (int r = 0; r < 4; ++r) {
            const int row = qb * 64 + w * 16 + lg * 4 + r;
            float o = Oa[t][r] * inv[r];
            Octx[((size_t)(b * 2048 + row)) * 1024 + h * 64 + t * 16 + lr] = (__bf16)o;
        }
}

// ---------------- launch ----------------
extern "C" void kernel_launch(void* const* d_in, const int* in_sizes, int n_in,
                              void* d_out, int out_size, void* d_ws, size_t ws_size,
                              hipStream_t stream) {
    const float* x         = (const float*)d_in[0];
    const float* attn_bias = (const float*)d_in[1];
    const float* W_qkv     = (const float*)d_in[2];
    const float* q_bias    = (const float*)d_in[3];
    const float* v_bias    = (const float*)d_in[4];
    const float* scale_mul = (const float*)d_in[5];
    const float* W_proj    = (const float*)d_in[6];
    const float* b_proj    = (const float*)d_in[7];
    float* out = (float*)d_out;

    char* ws = (char*)d_ws;
    size_t off = 0;
    auto alloc = [&](size_t bytes) {
        void* p = ws + off;
        off = (off + bytes + 255) & ~(size_t)255;
        return p;
    };
    __bf16* xb      = (__bf16*)alloc((size_t)4096 * 1024 * 2);
    __bf16* wqkvb   = (__bf16*)alloc((size_t)3072 * 1024 * 2);
    __bf16* wprojb  = (__bf16*)alloc((size_t)1024 * 1024 * 2);
    __bf16* Qw      = (__bf16*)alloc((size_t)BB * HH * LL * DD * 2);
    __bf16* Kw      = (__bf16*)alloc((size_t)BB * HH * LL * DD * 2);
    __bf16* Vw      = (__bf16*)alloc((size_t)BB * HH * LL * DD * 2);
    __bf16* Oc      = (__bf16*)alloc((size_t)4096 * 1024 * 2);
    __bf16* bias_bf = (__bf16*)alloc((size_t)2048 * 2048 * 2);
    __bf16* Vt      = (__bf16*)alloc((size_t)BB * HH * LL * DD * 2);

    cvt_bf16_kernel<<<4096, 256, 0, stream>>>(x, xb, 4096 * 1024 / 4);
    cvt_bf16_kernel<<<3072, 256, 0, stream>>>(W_qkv, wqkvb, 3072 * 1024 / 4);
    cvt_bf16_kernel<<<1024, 256, 0, stream>>>(W_proj, wprojb, 1024 * 1024 / 4);

    gemm_qkv_fused_kernel<<<dim3(32, 24), 256, 0, stream>>>(
        xb, wqkvb, q_bias, v_bias, scale_mul, Qw, Kw, Vw);

    bias_prep_kernel<<<2048, 256, 0, stream>>>(attn_bias, bias_bf);
    v_transpose_kernel<<<dim3(32, 32), 256, 0, stream>>>(Vw, Vt);

    attn_kernel<<<dim3(32, 32), 256, 0, stream>>>(Qw, Kw, Vt, bias_bf, scale_mul, Oc);

    gemm_proj_kernel<<<dim3(32, 8), 256, 0, stream>>>(
        Oc, wprojb, out, b_proj, 4096, 1024, 1024);
}